// Round 6
// baseline (332.154 us; speedup 1.0000x reference)
//
#include <hip/hip_runtime.h>

// y = x @ W^T + bias. x:[65536,512] f32, W:[512,512] f32, bias:[512] f32.
// R8: R7 + double-buffered LDS -> ONE lgkm-only barrier per K-tile.
//   R7 post-mortem: 106us, MfmaUtil 12.5%, all pipes idle. Single-buffer
//   forced 2 barriers/K-tile (read-drain before overwrite); with 1 block/CU
//   (acc 128 AGPR + 120 VGPR = 2 waves/SIMD) the lockstep phases expose
//   latency everywhere. bf16 tiles are 32 KB -> double-buffer fits (128 KB):
//   - cvt+ds_write(t+1) overlaps the 64-MFMA phase (other buffer)
//   - global loads issued in iter t-1, consumed in iter t: full-iteration
//     latency cover (~1500 cyc)
//   - vmcnt NEVER drained; one lgkm-only barrier per K-tile
//   Geometry unchanged (traffic-minimal): BM=BN=256, BK=64, 512 blk x 512
//   thr, X re-read 2x (L3), W 256 MB L2-resident, swizzled LDS (0 conflicts).

typedef __bf16 bf16x8 __attribute__((ext_vector_type(8)));
typedef float f32x4 __attribute__((ext_vector_type(4)));

#define BAR() do { asm volatile("s_waitcnt lgkmcnt(0)" ::: "memory"); \
  __builtin_amdgcn_s_barrier(); __builtin_amdgcn_sched_barrier(0); } while (0)

__global__ __launch_bounds__(512, 2)
void linear_db(const float* __restrict__ X, const float* __restrict__ W,
               const float* __restrict__ bias, float* __restrict__ Y) {
  constexpr int K = 512, N = 512;

  // 2 x (256 rows x 64 k bf16) per operand; 128 B rows; logical 16B-group g
  // of row r at physical group g ^ (r&7). 4 x 32 KB = 128 KB total.
  __shared__ __bf16 As[2][256 * 64];
  __shared__ __bf16 Bs[2][256 * 64];

  const int tid  = threadIdx.x;
  const int lane = tid & 63;
  const int wave = tid >> 6;

  // 512 blocks = 256 m x 2 n; n-sharers of an m-tile differ by 8 -> same XCD.
  const int id = blockIdx.x;
  const int m  = ((id >> 4) << 3) | (id & 7);
  const int n  = (id >> 3) & 1;
  const int bm = m << 8;
  const int bn = n << 8;

  const int wm = (wave >> 2) << 7;  // 0 / 128
  const int wn = (wave & 3) << 6;   // 0..192

  // staging: thread t -> rows (t>>3)+64j, 16B-group g = t&7
  const int srow  = tid >> 3;
  const int g     = tid & 7;
  const int wbyte = srow * 128 + ((g ^ (srow & 7)) << 4);  // + j*8192
  const float* Xst = X + (size_t)(bm + srow) * K + g * 8;
  const float* Wst = W + (size_t)(bn + srow) * K + g * 8;

  // frag-read: row = (wm|wn) + frag*16 + mrow, group (h*4+q)^(mrow&7)
  const int mrow = lane & 15;
  const int q    = lane >> 4;
  const int m7   = mrow & 7;
  const int ga0  = ((q ^ m7) << 4);
  const int ga1  = (((q + 4) ^ m7) << 4);
  const int arow = (wm + mrow) * 128;
  const int brow = (wn + mrow) * 128;

  float bj[4];
#pragma unroll
  for (int j = 0; j < 4; ++j) bj[j] = bias[bn + wn + j * 16 + mrow];

  f32x4 xs[4][2], ws[4][2];

  auto load_tile = [&](int kt) {
#pragma unroll
    for (int j = 0; j < 4; ++j) {
      const float* xp = Xst + kt + (size_t)j * 64 * K;
      xs[j][0] = *(const f32x4*)xp;
      xs[j][1] = *(const f32x4*)(xp + 4);
      const float* wp = Wst + kt + (size_t)j * 64 * K;
      ws[j][0] = *(const f32x4*)wp;
      ws[j][1] = *(const f32x4*)(wp + 4);
    }
  };

  auto cvt_write = [&](__bf16* Ab, __bf16* Bb) {
#pragma unroll
    for (int j = 0; j < 4; ++j) {
      bf16x8 av, bv;
#pragma unroll
      for (int e = 0; e < 4; ++e) {
        av[e]     = (__bf16)xs[j][0][e];
        av[e + 4] = (__bf16)xs[j][1][e];
        bv[e]     = (__bf16)ws[j][0][e];
        bv[e + 4] = (__bf16)ws[j][1][e];
      }
      *(bf16x8*)((char*)Ab + wbyte + j * 8192) = av;
      *(bf16x8*)((char*)Bb + wbyte + j * 8192) = bv;
    }
  };

  f32x4 acc[8][4] = {};

  // prologue: tile0 -> buf0; tile1 loads stay in flight across the barrier
  load_tile(0);
  cvt_write(As[0], Bs[0]);   // counted vmcnt on tile-0 loads
  load_tile(64);
  BAR();

#pragma unroll 2             // makes buffer index compile-time per iteration
  for (int t = 0; t < 8; ++t) {
    const int c = t & 1;
    const char* asb = (const char*)As[c] + arow;
    const char* bsb = (const char*)Bs[c] + brow;

    // MFMA phase on buf c (24 ds_read_b128 + 64 MFMA per wave); the
    // cvt+ds_write below targets buf c^1 and overlaps this on the LDS pipe.
#pragma unroll
    for (int h = 0; h < 2; ++h) {
      const int ga = h ? ga1 : ga0;
      bf16x8 bfr[4];
#pragma unroll
      for (int j = 0; j < 4; ++j)
        bfr[j] = *(const bf16x8*)(bsb + ga + j * 2048);
#pragma unroll
      for (int i2 = 0; i2 < 8; ++i2) {
        bf16x8 af = *(const bf16x8*)(asb + ga + i2 * 2048);
#pragma unroll
        for (int j = 0; j < 4; ++j)
          acc[i2][j] = __builtin_amdgcn_mfma_f32_16x16x32_bf16(af, bfr[j],
                                                               acc[i2][j], 0, 0, 0);
      }
    }

    if (t < 7) {
      // tile t+1 regs (loaded in iter t-1; vmcnt fully covered) -> buf c^1
      cvt_write(As[c ^ 1], Bs[c ^ 1]);
      if (t < 6) load_tile((t + 2) * 64);   // in flight across next iter
      BAR();  // lgkm-only: writes visible, reads of buf c done; no vmcnt drain
    }
  }

  // epilogue: C/D col = lane&15 (n), row = (lane>>4)*4 + r (m)
#pragma unroll
  for (int i2 = 0; i2 < 8; ++i2) {
#pragma unroll
    for (int r = 0; r < 4; ++r) {
      const size_t gr = (size_t)(bm + wm + i2 * 16 + q * 4 + r);
      float* yp = Y + gr * N + bn + wn + mrow;
#pragma unroll
      for (int j = 0; j < 4; ++j)
        __builtin_nontemporal_store(acc[i2][j][r] + bj[j], yp + j * 16);
    }
  }
}

extern "C" void kernel_launch(void* const* d_in, const int* in_sizes, int n_in,
                              void* d_out, int out_size, void* d_ws, size_t ws_size,
                              hipStream_t stream) {
  const float* X = (const float*)d_in[0];
  const float* W = (const float*)d_in[1];
  const float* b = (const float*)d_in[2];
  float* Y = (float*)d_out;
  linear_db<<<dim3(512), 512, 0, stream>>>(X, W, b, Y);
}

// Round 7
// 274.973 us; speedup vs baseline: 1.2080x; 1.2080x over previous
//
#include <hip/hip_runtime.h>

// y = x @ W^T + bias. x:[65536,512] f32, W:[512,512] f32, bias:[512] f32.
// R9: global_load_lds DMA staging (the concurrency fix).
//   R7 (reg-staged, 106us): all pipes <30% busy. Little's law: 16x16B
//   in-flight loads/wave x 8 waves/CU = 2KB/CU -> ~4-6 TB/s vector-memory
//   ceiling = the measured rate. R8 (dbuf regs) spilled (WRITE +139MB).
//   Fix: stage f32 tiles straight to LDS via global_load_lds (no VGPRs
//   held -> a full 64KB prefetched tile in flight per CU), convert
//   f32->bf16 at frag-read time (VALU idle). BK=32, double-buffered
//   (4 x 32KB = 128KB LDS). Counted vmcnt(8) per K-tile, never drained;
//   lgkm-only second barrier. Swizzle on the GLOBAL SOURCE side (linear
//   LDS dest per m104/m173): lane l loads k-group (l&7)^(l>>3) so
//   LDS[row][slot] holds group slot^(row&7); reader XORs the same ->
//   bank-balanced (R7 verified 0 conflicts with this involution).
//   Geometry unchanged: BM=BN=256, 512 blk x 512 thr, 8 waves (2m x 4n),
//   acc[8][4]=128 AGPR; n-pair of each m-tile on same XCD (L2 share).

typedef __bf16 bf16x8 __attribute__((ext_vector_type(8)));
typedef float f32x4 __attribute__((ext_vector_type(4)));
typedef __attribute__((address_space(3))) unsigned int lds_uint;
typedef const __attribute__((address_space(1))) unsigned int gbl_uint;

__global__ __launch_bounds__(512, 2)
void linear_dma(const float* __restrict__ X, const float* __restrict__ W,
                const float* __restrict__ bias, float* __restrict__ Y) {
  constexpr int K = 512, N = 512;

  // f32 tiles [256 rows][32 k], 128 B rows, 32 KB each, double-buffered.
  __shared__ float As[2][256 * 32];
  __shared__ float Bs[2][256 * 32];

  const int tid  = threadIdx.x;
  const int lane = tid & 63;
  const int wave = tid >> 6;

  // 512 blocks = 256 m x 2 n; n-sharers of an m-tile differ by 8 -> same XCD.
  const int id = blockIdx.x;
  const int m  = ((id >> 4) << 3) | (id & 7);
  const int n  = (id >> 3) & 1;
  const int bm = m << 8;
  const int bn = n << 8;

  const int wm = (wave >> 2) << 7;  // 0 / 128
  const int wn = (wave & 3) << 6;   // 0..192

  // ---- DMA staging map ----
  // instr a (0..3) of wave w covers rows w*32 + a*8 .. +7 (1024 B LDS).
  // lane l: row_local = w*32 + a*8 + (l>>3); writes LDS slot l&7 (HW: lane*16);
  // loads global k-group (l&7)^(l>>3)  [= slot ^ (row&7), the involution].
  const int r8 = lane >> 3;                  // 0..7
  const int sl = ((lane & 7) ^ r8) * 4;      // float offset of 16B group
  const float* Xsg = X + (size_t)(bm + wave * 32 + r8) * K + sl;
  const float* Wsg = W + (size_t)(bn + wave * 32 + r8) * K + sl;

  auto issue_tile = [&](int t, int c) {
    const int kt = t * 32;
    char* la = (char*)(&As[c][0]) + wave * 4096;
    char* lb = (char*)(&Bs[c][0]) + wave * 4096;
#pragma unroll
    for (int a = 0; a < 4; ++a) {
      __builtin_amdgcn_global_load_lds(
          (gbl_uint*)(Xsg + (size_t)a * 8 * K + kt),
          (lds_uint*)(la + a * 1024), 16, 0, 0);
      __builtin_amdgcn_global_load_lds(
          (gbl_uint*)(Wsg + (size_t)a * 8 * K + kt),
          (lds_uint*)(lb + a * 1024), 16, 0, 0);
    }
  };

  // ---- frag-read constants ----
  // A/B frag: row = (wm|wn) + frag*16 + mrow; k = q*8..q*8+7 -> logical
  // 16B-groups 2q, 2q+1; physical slot = logical ^ (row&7), row&7 = mrow&7.
  const int mrow = lane & 15;
  const int q    = lane >> 4;
  const int m7   = mrow & 7;
  const int sA0  = ((2 * q) ^ m7) << 4;       // byte offset within row
  const int sA1  = ((2 * q + 1) ^ m7) << 4;
  const int arowb = (wm + mrow) * 128;
  const int browb = (wn + mrow) * 128;

  f32x4 acc[8][4] = {};

  // prologue: tiles 0 and 1 in flight (16 DMA instrs/wave, 0 VGPRs held)
  issue_tile(0, 0);
  issue_tile(1, 1);

#pragma unroll 1
  for (int t = 0; t < 16; ++t) {
    const int c = t & 1;
    // tile t's 8 loads done; tile t+1's 8 stay in flight (T4: never drain)
    if (t < 15) asm volatile("s_waitcnt vmcnt(8)" ::: "memory");
    else        asm volatile("s_waitcnt vmcnt(0)" ::: "memory");
    __builtin_amdgcn_s_barrier();
    __builtin_amdgcn_sched_barrier(0);

    const char* ac = (const char*)(&As[c][0]) + arowb;
    const char* bc = (const char*)(&Bs[c][0]) + browb;

    bf16x8 bfrag[4];
#pragma unroll
    for (int j = 0; j < 4; ++j) {
      f32x4 b0 = *(const f32x4*)(bc + j * 2048 + sA0);
      f32x4 b1 = *(const f32x4*)(bc + j * 2048 + sA1);
      bf16x8 v;
#pragma unroll
      for (int e = 0; e < 4; ++e) {
        v[e]     = (__bf16)b0[e];
        v[e + 4] = (__bf16)b1[e];
      }
      bfrag[j] = v;
    }
#pragma unroll
    for (int i2 = 0; i2 < 8; ++i2) {
      f32x4 a0 = *(const f32x4*)(ac + i2 * 2048 + sA0);
      f32x4 a1 = *(const f32x4*)(ac + i2 * 2048 + sA1);
      bf16x8 av;
#pragma unroll
      for (int e = 0; e < 4; ++e) {
        av[e]     = (__bf16)a0[e];
        av[e + 4] = (__bf16)a1[e];
      }
#pragma unroll
      for (int j = 0; j < 4; ++j)
        acc[i2][j] = __builtin_amdgcn_mfma_f32_16x16x32_bf16(av, bfrag[j],
                                                             acc[i2][j], 0, 0, 0);
    }

    if (t < 15) {
      // all waves' ds_reads of buf c retired before any new DMA targets it
      asm volatile("s_waitcnt lgkmcnt(0)" ::: "memory");
      __builtin_amdgcn_s_barrier();
      __builtin_amdgcn_sched_barrier(0);
      if (t < 14) issue_tile(t + 2, c);
    }
  }

  // ---- epilogue: C/D col = lane&15 (n), row = (lane>>4)*4 + r (m) ----
  float bj[4];
#pragma unroll
  for (int j = 0; j < 4; ++j) bj[j] = bias[bn + wn + j * 16 + mrow];
#pragma unroll
  for (int i2 = 0; i2 < 8; ++i2) {
#pragma unroll
    for (int r = 0; r < 4; ++r) {
      const size_t gr = (size_t)(bm + wm + i2 * 16 + q * 4 + r);
      float* yp = Y + gr * N + bn + wn + mrow;
#pragma unroll
      for (int j = 0; j < 4; ++j)
        __builtin_nontemporal_store(acc[i2][j][r] + bj[j], yp + j * 16);
    }
  }
}

extern "C" void kernel_launch(void* const* d_in, const int* in_sizes, int n_in,
                              void* d_out, int out_size, void* d_ws, size_t ws_size,
                              hipStream_t stream) {
  const float* X = (const float*)d_in[0];
  const float* W = (const float*)d_in[1];
  const float* b = (const float*)d_in[2];
  float* Y = (float*)d_out;
  linear_dma<<<dim3(512), 512, 0, stream>>>(X, W, b, Y);
}